// Round 15
// baseline (54.519 us; speedup 1.0000x reference)
//
#include <hip/hip_runtime.h>
#include <hip/hip_fp16.h>

#define DIN 1024
#define H_SZ 512
#define OUT_SZ 512
#define EPSF 1e-8f

typedef __attribute__((ext_vector_type(8))) short short8v;   // 8 bf16 = 4 VGPRs
typedef __attribute__((ext_vector_type(4))) float f32x4;
typedef _Float16 half2v __attribute__((ext_vector_type(2)));

// Canberra core: 4 packed ops per 2 terms (r13-proven, absmax 1.5e-5).
static __device__ inline void canb2f(unsigned hu, unsigned wu, unsigned& a) {
    unsigned mn, sm, y;
    asm("v_pk_min_f16 %0, %1, %2" : "=v"(mn) : "v"(hu), "v"(wu));
    asm("v_pk_add_f16 %0, %1, %2" : "=v"(sm) : "v"(hu), "v"(wu));
    y = 0x77997799u - sm;                           // magic rcp (balanced +-5%, decorrelates)
    asm("v_pk_fma_f16 %0, %1, %2, %0" : "+v"(a) : "v"(mn), "v"(y));
}

// pack 2 fp32 -> 2 bf16 in one op (gfx950; RNE)
static __device__ inline unsigned cvtpk(float lo, float hi) {
    unsigned u;
    asm("v_cvt_pk_bf16_f32 %0, %1, %2" : "=v"(u) : "v"(lo), "v"(hi));
    return u;
}

// ---------------- GEMM v11: LDS-FREE direct-fragment MFMA ----------------
// Each wave loads its own A/B fragments straight from global (L2-served, XCD-swizzled),
// converts in-register, MFMAs. ZERO barriers in the K-loop (vs 9 in the staged version).
// 8 waves = 4 quadrants x 2 k-halves; k-half reduce via 4KB LDS + 2 barriers at the end.
// Fragment rows: lane lr = l&15 -> row m0+lr; k-segment lk = (l>>4)*8, step stride 32 f32
// (128B immediate offsets, no addr math in loop).
__global__ __launch_bounds__(512, 4) void gemm11(const float* __restrict__ x,
                                                 const float* __restrict__ W1,
                                                 const float* __restrict__ b1,
                                                 const float* __restrict__ Wd,
                                                 unsigned short* __restrict__ hh,
                                                 unsigned short* __restrict__ wh) {
    __shared__ float red[4][64][4];
    const int t  = threadIdx.x;

    // bijective XCD swizzle (r12-proven): flat -> (xcd, idx) -> (b-tile, o-tile)
    const int flat = blockIdx.x + 32 * blockIdx.y;   // 0..511
    const int xcd  = flat & 7;
    const int idx  = flat >> 3;
    const int bt   = (xcd >> 1) * 8 + (idx & 7);     // b-tile 0..31
    const int ot   = (xcd & 1) * 8 + (idx >> 3);     // o-tile 0..15
    const int b0 = bt * 32;
    const int o0 = ot * 32;

    const int w  = t >> 6;
    const int l  = t & 63;
    const int q  = w & 3;
    const int kh = w >> 2;             // k-half 0/1
    const int m0 = (q >> 1) * 16;
    const int n0 = (q & 1) * 16;
    const int lr = l & 15;
    const int lk = (l >> 4) * 8;       // k-offset of this lane's 8 contiguous elements

    f32x4 acc = {0.f, 0.f, 0.f, 0.f};
    const float4* pA = reinterpret_cast<const float4*>(
        &x [(size_t)(b0 + m0 + lr) * DIN + kh * 512 + lk]);
    const float4* pB = reinterpret_cast<const float4*>(
        &W1[(size_t)(o0 + n0 + lr) * DIN + kh * 512 + lk]);

    #pragma unroll
    for (int s = 0; s < 16; ++s) {     // 16 k-steps of 32 (per k-half)
        const float4 a0 = pA[s * 8];
        const float4 a1 = pA[s * 8 + 1];
        const float4 bq0 = pB[s * 8];
        const float4 bq1 = pB[s * 8 + 1];
        uint4 av, bv;
        av.x = cvtpk(a0.x, a0.y);  av.y = cvtpk(a0.z, a0.w);
        av.z = cvtpk(a1.x, a1.y);  av.w = cvtpk(a1.z, a1.w);
        bv.x = cvtpk(bq0.x, bq0.y); bv.y = cvtpk(bq0.z, bq0.w);
        bv.z = cvtpk(bq1.x, bq1.y); bv.w = cvtpk(bq1.z, bq1.w);
        acc = __builtin_amdgcn_mfma_f32_16x16x32_bf16(
            __builtin_bit_cast(short8v, av), __builtin_bit_cast(short8v, bv), acc, 0, 0, 0);
    }

    __syncthreads();
    if (kh == 1) {
        #pragma unroll
        for (int r = 0; r < 4; ++r) red[q][l][r] = acc[r];
    }
    __syncthreads();
    if (kh == 0) {
        // C/D layout (m89-verified): col = lane&15, row = (lane>>4)*4 + reg
        const int col = o0 + n0 + lr;
        const float bias = b1[col];
        #pragma unroll
        for (int r = 0; r < 4; ++r) {
            const float v = acc[r] + red[q][l][r] + bias;
            const int m = b0 + m0 + (l >> 4) * 4 + r;
            hh[(size_t)m * H_SZ + col] = __half_as_ushort(__float2half(fmaxf(v, 0.0f)));
        }
    }
    // Wd preprocess: 262144 elems == 512 blocks * 512 thr. +0 only (no -0 bits).
    const int gid = flat * 512 + t;
    const float wv0 = Wd[gid];
    wh[gid] = __half_as_ushort(__float2half(wv0 > 0.f ? wv0 : 0.f));
}

// ---------------- Canberra v7 (r13-exact revert: the 32.0 us config) ----------------
__global__ __launch_bounds__(512, 8) void canberra7(const unsigned short* __restrict__ hh,
                                                    const unsigned short* __restrict__ wh,
                                                    float* __restrict__ out) {
    __shared__ unsigned hs[32][132];   // 32 b-rows x 128 uints (256 k) + pad 4
    __shared__ unsigned ws[16][132];   // 16 o-rows x 128 uints + pad 4
    const int t  = threadIdx.x;
    const int b0 = blockIdx.x * 32;
    const int o0 = blockIdx.y * 16;
    const unsigned* hu = reinterpret_cast<const unsigned*>(hh);
    const unsigned* wu = reinterpret_cast<const unsigned*>(wh);

    const int ks = t >> 6;     // 0..7, wave-uniform k-slice
    const int l  = t & 63;
    const int bi = l >> 3;     // 0..7
    const int oj = l & 7;      // 0..7

    unsigned acc[4][2] = {};

    for (int ch = 0; ch < 2; ++ch) {    // two 256-k chunks
        if (ch) __syncthreads();        // previous chunk's reads complete
        #pragma unroll
        for (int r = 0; r < 2; ++r) {
            const int s = t + r * 512;
            const int row = s >> 5;         // 0..31
            const int c4  = s & 31;         // uint4 col
            *reinterpret_cast<uint4*>(&hs[row][c4 * 4]) =
                *reinterpret_cast<const uint4*>(&hu[(size_t)(b0 + row) * 256 + ch * 128 + c4 * 4]);
        }
        {
            const int row = t >> 5;         // 0..15
            const int c4  = t & 31;
            *reinterpret_cast<uint4*>(&ws[row][c4 * 4]) =
                *reinterpret_cast<const uint4*>(&wu[(size_t)(o0 + row) * 256 + ch * 128 + c4 * 4]);
        }
        __syncthreads();

        #pragma unroll
        for (int g = 0; g < 4; ++g) {   // 4 uint4-cols = 32 k per thread per chunk
            const int col = ks * 16 + g * 4;
            uint4 hv[4], wv[2];
            #pragma unroll
            for (int c = 0; c < 4; ++c)
                hv[c] = *reinterpret_cast<const uint4*>(&hs[bi + 8 * c][col]);
            #pragma unroll
            for (int d = 0; d < 2; ++d)
                wv[d] = *reinterpret_cast<const uint4*>(&ws[oj + 8 * d][col]);
            #pragma unroll
            for (int c = 0; c < 4; ++c) {
                #pragma unroll
                for (int d = 0; d < 2; ++d) {
                    canb2f(hv[c].x, wv[d].x, acc[c][d]);
                    canb2f(hv[c].y, wv[d].y, acc[c][d]);
                    canb2f(hv[c].z, wv[d].z, acc[c][d]);
                    canb2f(hv[c].w, wv[d].w, acc[c][d]);
                }
            }
        }
    }

    float p[8];
    #pragma unroll
    for (int c = 0; c < 4; ++c)
        #pragma unroll
        for (int d = 0; d < 2; ++d) {
            const half2v av = __builtin_bit_cast(half2v, acc[c][d]);
            p[c * 2 + d] = (float)av.x + (float)av.y;
        }

    // 8-way k-reduce, transposed conflict-free layout (r8-proven): bank = lane%32
    __syncthreads();
    float* red = reinterpret_cast<float*>(&hs[0][0]);   // [8][448] floats = 14.3 KB
    if (ks > 0) {
        const int slot = (ks - 1) * 64 + l;
        #pragma unroll
        for (int i = 0; i < 8; ++i) red[i * 448 + slot] = p[i];
    }
    __syncthreads();
    if (ks == 0) {
        #pragma unroll
        for (int q = 0; q < 7; ++q) {
            #pragma unroll
            for (int i = 0; i < 8; ++i) p[i] += red[i * 448 + q * 64 + l];
        }
        #pragma unroll
        for (int c = 0; c < 4; ++c) {
            #pragma unroll
            for (int d = 0; d < 2; ++d) {
                float dd = 512.0f - 2.0f * p[c * 2 + d] + EPSF;
                dd = fminf(fmaxf(dd, EPSF), 1000000.0f);
                out[(size_t)(b0 + bi + 8 * c) * OUT_SZ + o0 + oj + 8 * d] = 1.0f / dd;
            }
        }
    }
}

extern "C" void kernel_launch(void* const* d_in, const int* in_sizes, int n_in,
                              void* d_out, int out_size, void* d_ws, size_t ws_size,
                              hipStream_t stream) {
    const float* x  = (const float*)d_in[0];
    const float* W1 = (const float*)d_in[1];
    const float* b1 = (const float*)d_in[2];
    const float* Wd = (const float*)d_in[3];
    float* out = (float*)d_out;
    unsigned short* hh = (unsigned short*)d_ws;                          // 1 MB fp16 h
    unsigned short* wh = (unsigned short*)((char*)d_ws + (1u << 20));    // 0.5 MB fp16 relu(Wd)

    gemm11<<<dim3(32, 16), 512, 0, stream>>>(x, W1, b1, Wd, hh, wh);
    canberra7<<<dim3(32, 32), 512, 0, stream>>>(hh, wh, out);
}

// Round 16
// 32.002 us; speedup vs baseline: 1.7036x; 1.7036x over previous
//
#include <hip/hip_runtime.h>
#include <hip/hip_fp16.h>

#define DIN 1024
#define H_SZ 512
#define OUT_SZ 512
#define EPSF 1e-8f

typedef __attribute__((ext_vector_type(8))) short short8v;   // 8 bf16 = 4 VGPRs
typedef __attribute__((ext_vector_type(4))) float f32x4;
typedef _Float16 half2v __attribute__((ext_vector_type(2)));

// Canberra core: 4 packed ops per 2 terms (r13-proven, absmax 1.5e-5).
// term = min(h,w') * magicrcp(h+w'); y_bits = 0x7799 - x_bits (balanced +-5% rel err,
// decorrelates over 512-term sum). sm<=8 -> no cross-half borrow; sm=0 -> mn=0 -> term=0.
static __device__ inline void canb2f(unsigned hu, unsigned wu, unsigned& a) {
    unsigned mn, sm, y;
    asm("v_pk_min_f16 %0, %1, %2" : "=v"(mn) : "v"(hu), "v"(wu));
    asm("v_pk_add_f16 %0, %1, %2" : "=v"(sm) : "v"(hu), "v"(wu));
    y = 0x77997799u - sm;                           // v_sub_u32, literal in src0
    asm("v_pk_fma_f16 %0, %1, %2, %0" : "+v"(a) : "v"(mn), "v"(y));
}

// pack 2 fp32 -> 2 bf16 in one op (gfx950; RNE)
static __device__ inline unsigned cvtpk(float lo, float hi) {
    unsigned u;
    asm("v_cvt_pk_bf16_f32 %0, %1, %2" : "=v"(u) : "v"(lo), "v"(hi));
    return u;
}

// ---------------- GEMM v10 (r12/r13 exact, the 32.0us-config): XCD swizzle + staged dbuf ----------
__global__ __launch_bounds__(512, 4) void gemm10(const float* __restrict__ x,
                                                 const float* __restrict__ W1,
                                                 const float* __restrict__ b1,
                                                 const float* __restrict__ Wd,
                                                 unsigned short* __restrict__ hh,
                                                 unsigned short* __restrict__ wh) {
    __shared__ unsigned short As[2][2][32][72];   // [khalf][buf][m][k]
    __shared__ unsigned short Bs[2][2][32][72];
    __shared__ float red[4][64][4];
    const int t  = threadIdx.x;

    // bijective XCD swizzle: flat -> (xcd, idx) -> (b-tile, o-tile)
    const int flat = blockIdx.x + 32 * blockIdx.y;   // 0..511, dispatch order
    const int xcd  = flat & 7;
    const int idx  = flat >> 3;                      // 0..63 within XCD
    const int bt   = (xcd >> 1) * 8 + (idx & 7);     // b-tile 0..31
    const int ot   = (xcd & 1) * 8 + (idx >> 3);     // o-tile 0..15
    const int b0 = bt * 32;
    const int o0 = ot * 32;

    const int w  = t >> 6;
    const int l  = t & 63;
    const int q  = w & 3;
    const int kh = w >> 2;             // k-half 0/1
    const int m0 = (q >> 1) * 16;
    const int n0 = (q & 1) * 16;
    const int lr = l & 15;
    const int lk = (l >> 4) * 8;
    const int th = t & 255;
    const int ar = th >> 3;            // 0..31
    const int ko = (th & 7) * 8;       // 0..56

    f32x4 acc = {0.f, 0.f, 0.f, 0.f};
    const float* arow = &x [(size_t)(b0 + ar) * DIN + kh * 512 + ko];
    const float* brow = &W1[(size_t)(o0 + ar) * DIN + kh * 512 + ko];

    float4 pa0[2], pa1[2], pb0[2], pb1[2];   // depth-2 prefetch ring
    #pragma unroll
    for (int i = 0; i < 2; ++i) {
        pa0[i] = *reinterpret_cast<const float4*>(arow + i * 64);
        pa1[i] = *reinterpret_cast<const float4*>(arow + i * 64 + 4);
        pb0[i] = *reinterpret_cast<const float4*>(brow + i * 64);
        pb1[i] = *reinterpret_cast<const float4*>(brow + i * 64 + 4);
    }

    #pragma unroll
    for (int it = 0; it < 8; ++it) {
        const int sl  = it & 1;        // reg ring slot == LDS dbuf
        uint4 av, bv;
        av.x = cvtpk(pa0[sl].x, pa0[sl].y);
        av.y = cvtpk(pa0[sl].z, pa0[sl].w);
        av.z = cvtpk(pa1[sl].x, pa1[sl].y);
        av.w = cvtpk(pa1[sl].z, pa1[sl].w);
        bv.x = cvtpk(pb0[sl].x, pb0[sl].y);
        bv.y = cvtpk(pb0[sl].z, pb0[sl].w);
        bv.z = cvtpk(pb1[sl].x, pb1[sl].y);
        bv.w = cvtpk(pb1[sl].z, pb1[sl].w);
        *reinterpret_cast<uint4*>(&As[kh][sl][ar][ko]) = av;
        *reinterpret_cast<uint4*>(&Bs[kh][sl][ar][ko]) = bv;
        __syncthreads();   // dbuf safe (proven r5-r13)
        if (it + 2 < 8) {  // prefetch 2 iters ahead into the slot just consumed
            pa0[sl] = *reinterpret_cast<const float4*>(arow + (it + 2) * 64);
            pa1[sl] = *reinterpret_cast<const float4*>(arow + (it + 2) * 64 + 4);
            pb0[sl] = *reinterpret_cast<const float4*>(brow + (it + 2) * 64);
            pb1[sl] = *reinterpret_cast<const float4*>(brow + (it + 2) * 64 + 4);
        }
        #pragma unroll
        for (int s = 0; s < 2; ++s) {
            const short8v af = *reinterpret_cast<const short8v*>(&As[kh][sl][m0 + lr][s * 32 + lk]);
            const short8v bf = *reinterpret_cast<const short8v*>(&Bs[kh][sl][n0 + lr][s * 32 + lk]);
            acc = __builtin_amdgcn_mfma_f32_16x16x32_bf16(af, bf, acc, 0, 0, 0);
        }
    }
    __syncthreads();
    if (kh == 1) {
        #pragma unroll
        for (int r = 0; r < 4; ++r) red[q][l][r] = acc[r];
    }
    __syncthreads();
    if (kh == 0) {
        // C/D layout (m89-verified): col = lane&15, row = (lane>>4)*4 + reg
        const int col = o0 + n0 + lr;
        const float bias = b1[col];
        #pragma unroll
        for (int r = 0; r < 4; ++r) {
            const float v = acc[r] + red[q][l][r] + bias;
            const int m = b0 + m0 + (l >> 4) * 4 + r;
            hh[(size_t)m * H_SZ + col] = __half_as_ushort(__float2half(fmaxf(v, 0.0f)));
        }
    }
    // Wd preprocess: 262144 elems == 512 blocks * 512 thr (flat covers 0..511 bijectively).
    const int gid = flat * 512 + t;
    const float wv0 = Wd[gid];
    wh[gid] = __half_as_ushort(__float2half(wv0 > 0.f ? wv0 : 0.f));
}

// ---------------- Canberra v7 (r13 exact, the 32.0us-config) ----------------
__global__ __launch_bounds__(512, 8) void canberra7(const unsigned short* __restrict__ hh,
                                                    const unsigned short* __restrict__ wh,
                                                    float* __restrict__ out) {
    __shared__ unsigned hs[32][132];   // 32 b-rows x 128 uints (256 k) + pad 4
    __shared__ unsigned ws[16][132];   // 16 o-rows x 128 uints + pad 4
    const int t  = threadIdx.x;
    const int b0 = blockIdx.x * 32;
    const int o0 = blockIdx.y * 16;
    const unsigned* hu = reinterpret_cast<const unsigned*>(hh);
    const unsigned* wu = reinterpret_cast<const unsigned*>(wh);

    const int ks = t >> 6;     // 0..7, wave-uniform k-slice
    const int l  = t & 63;
    const int bi = l >> 3;     // 0..7
    const int oj = l & 7;      // 0..7

    unsigned acc[4][2] = {};

    for (int ch = 0; ch < 2; ++ch) {    // two 256-k chunks
        if (ch) __syncthreads();        // previous chunk's reads complete
        #pragma unroll
        for (int r = 0; r < 2; ++r) {
            const int s = t + r * 512;
            const int row = s >> 5;         // 0..31
            const int c4  = s & 31;         // uint4 col
            *reinterpret_cast<uint4*>(&hs[row][c4 * 4]) =
                *reinterpret_cast<const uint4*>(&hu[(size_t)(b0 + row) * 256 + ch * 128 + c4 * 4]);
        }
        {
            const int row = t >> 5;         // 0..15
            const int c4  = t & 31;
            *reinterpret_cast<uint4*>(&ws[row][c4 * 4]) =
                *reinterpret_cast<const uint4*>(&wu[(size_t)(o0 + row) * 256 + ch * 128 + c4 * 4]);
        }
        __syncthreads();

        #pragma unroll
        for (int g = 0; g < 4; ++g) {   // 4 uint4-cols = 32 k per thread per chunk
            const int col = ks * 16 + g * 4;
            uint4 hv[4], wv[2];
            #pragma unroll
            for (int c = 0; c < 4; ++c)
                hv[c] = *reinterpret_cast<const uint4*>(&hs[bi + 8 * c][col]);
            #pragma unroll
            for (int d = 0; d < 2; ++d)
                wv[d] = *reinterpret_cast<const uint4*>(&ws[oj + 8 * d][col]);
            #pragma unroll
            for (int c = 0; c < 4; ++c) {
                #pragma unroll
                for (int d = 0; d < 2; ++d) {
                    canb2f(hv[c].x, wv[d].x, acc[c][d]);
                    canb2f(hv[c].y, wv[d].y, acc[c][d]);
                    canb2f(hv[c].z, wv[d].z, acc[c][d]);
                    canb2f(hv[c].w, wv[d].w, acc[c][d]);
                }
            }
        }
    }

    float p[8];
    #pragma unroll
    for (int c = 0; c < 4; ++c)
        #pragma unroll
        for (int d = 0; d < 2; ++d) {
            const half2v av = __builtin_bit_cast(half2v, acc[c][d]);
            p[c * 2 + d] = (float)av.x + (float)av.y;
        }

    // 8-way k-reduce, transposed conflict-free layout (r8-proven): bank = lane%32
    __syncthreads();
    float* red = reinterpret_cast<float*>(&hs[0][0]);   // [8][448] floats = 14.3 KB
    if (ks > 0) {
        const int slot = (ks - 1) * 64 + l;
        #pragma unroll
        for (int i = 0; i < 8; ++i) red[i * 448 + slot] = p[i];
    }
    __syncthreads();
    if (ks == 0) {
        #pragma unroll
        for (int q = 0; q < 7; ++q) {
            #pragma unroll
            for (int i = 0; i < 8; ++i) p[i] += red[i * 448 + q * 64 + l];
        }
        #pragma unroll
        for (int c = 0; c < 4; ++c) {
            #pragma unroll
            for (int d = 0; d < 2; ++d) {
                float dd = 512.0f - 2.0f * p[c * 2 + d] + EPSF;
                dd = fminf(fmaxf(dd, EPSF), 1000000.0f);
                out[(size_t)(b0 + bi + 8 * c) * OUT_SZ + o0 + oj + 8 * d] = 1.0f / dd;
            }
        }
    }
}

extern "C" void kernel_launch(void* const* d_in, const int* in_sizes, int n_in,
                              void* d_out, int out_size, void* d_ws, size_t ws_size,
                              hipStream_t stream) {
    const float* x  = (const float*)d_in[0];
    const float* W1 = (const float*)d_in[1];
    const float* b1 = (const float*)d_in[2];
    const float* Wd = (const float*)d_in[3];
    float* out = (float*)d_out;
    unsigned short* hh = (unsigned short*)d_ws;                          // 1 MB fp16 h
    unsigned short* wh = (unsigned short*)((char*)d_ws + (1u << 20));    // 0.5 MB fp16 relu(Wd)

    gemm10<<<dim3(32, 16), 512, 0, stream>>>(x, W1, b1, Wd, hh, wh);
    canberra7<<<dim3(32, 32), 512, 0, stream>>>(hh, wh, out);
}